// Round 5
// baseline (730.306 us; speedup 1.0000x reference)
//
#include <hip/hip_runtime.h>
#include <hip/hip_bf16.h>
#include <cstdint>

#define KDIM 512
#define BM 128
#define BN 512      // full N: A is read exactly once
#define BK 32
#define M_MAIN 100352   // 512*196
#define NPIX 196
#define BATCH 512

typedef float f32x4 __attribute__((ext_vector_type(4)));
typedef short s16x8 __attribute__((ext_vector_type(8)));

__device__ __forceinline__ short f2bf(float f) {
    uint32_t u = __float_as_uint(f);
    uint32_t r = u + 0x7FFFu + ((u >> 16) & 1u);   // round-to-nearest-even
    return (short)(r >> 16);
}

__device__ __forceinline__ void gload_lds16(const void* g, void* l) {
    __builtin_amdgcn_global_load_lds(
        (const __attribute__((address_space(1))) void*)g,
        (__attribute__((address_space(3))) void*)l, 16, 0, 0);
}

__device__ __forceinline__ uint32_t pkbf(float lo, float hi) {
    __hip_bfloat162 p = __float22bfloat162_rn(float2{lo, hi});
    return *reinterpret_cast<uint32_t*>(&p);
}

// Transpose + convert W [K][A] fp32 -> Wt [A][K] bf16 for both weight matrices.
__global__ void prep_w(const float* __restrict__ W_enc, const float* __restrict__ W_dec,
                       short* __restrict__ Wt_enc, short* __restrict__ Wt_dec) {
    int a = blockIdx.x;
    int k = threadIdx.x;
    const float* W = blockIdx.y ? W_dec : W_enc;
    short* Wt = blockIdx.y ? Wt_dec : Wt_enc;
    Wt[a * KDIM + k] = f2bf(W[(size_t)k * KDIM + a]);
}

// 512 threads = 8 waves as 2(M) x 4(N); per-wave output 64x128 (acc[4][8]).
// Block covers full N=512 -> A tile read once; energy row-sum completed in-block.
// BK=32: each LDS row = 4 16B slots; XOR-swizzle slot s of row r -> s^(r&3)
// (bijective, conflict-free for ds_write_b128, gload_lds, ds_read_b128).
// EPI==0: out[row][col] = acc + b1[col] + b2[col]   (att_dec' precompute)
// EPI==1: out[row] = full energy = sum_cols relu(acc + attdec[row/196][col]) * wfull[col]
template <int EPI>
__launch_bounds__(512, 4)
__global__ void gemm_fused(const float* __restrict__ A, int M,
                           const short* __restrict__ Bt,
                           const float* __restrict__ b1, const float* __restrict__ b2,
                           const float* __restrict__ attdec, const float* __restrict__ wfull,
                           float* __restrict__ outp) {
    __shared__ short lds_a[2][BM][BK];   // 16 KB
    __shared__ short lds_b[2][BN][BK];   // 64 KB

    const int tid = threadIdx.x;
    const int wave = tid >> 6;
    const int lane = tid & 63;
    const int wm = wave >> 2;       // 2 waves along M
    const int wn = wave & 3;        // 4 waves along N
    // XCD-aware bijective swizzle when grid % 8 == 0; identity otherwise
    const int nwg = gridDim.x;
    int swzb;
    if ((nwg & 7) == 0) {
        int q = nwg >> 3;
        swzb = (blockIdx.x & 7) * q + (blockIdx.x >> 3);
    } else {
        swzb = blockIdx.x;
    }
    const int r0 = swzb * BM;

    f32x4 areg[2];                  // 8 f32 per thread per K-step

    // A tile: 128 rows x 32 f32; thread owns 8 f32: row=tid>>2, cols (tid&3)*8..+7
    auto loadA = [&](int kt) {
        int row = tid >> 2, c8 = (tid & 3) * 8;
        const float* p = A + (size_t)(r0 + row) * KDIM + kt * BK + c8;
        areg[0] = *(const f32x4*)p;
        areg[1] = *(const f32x4*)(p + 4);
    };
    auto writeA = [&](int buf) {
        int row = tid >> 2;
        int slot = (tid & 3) ^ (row & 3);
        uint4 w;
        w.x = pkbf(areg[0][0], areg[0][1]);
        w.y = pkbf(areg[0][2], areg[0][3]);
        w.z = pkbf(areg[1][0], areg[1][1]);
        w.w = pkbf(areg[1][2], areg[1][3]);
        *reinterpret_cast<uint4*>(&lds_a[buf][row][slot * 8]) = w;
    };
    auto stageB = [&](int buf, int kt) {
#pragma unroll
        for (int i = 0; i < 4; ++i) {
            int rb = wave * 64 + i * 16;    // 16 rows per issue (64 lanes * 16B, 64B rows)
            // lane l -> physical (row rb+(l>>2), slot l&3); pre-swizzle SOURCE column
            // so physical slot p holds logical slot p^(row&3)  (rule #21).
            int srcslot = (lane & 3) ^ ((lane >> 2) & 3);
            const short* g = Bt + (size_t)(rb + (lane >> 2)) * KDIM + kt * BK + srcslot * 8;
            gload_lds16(g, &lds_b[buf][rb][0]);
        }
    };

    f32x4 acc[4][8];
#pragma unroll
    for (int i = 0; i < 4; ++i)
#pragma unroll
        for (int j = 0; j < 8; ++j)
            acc[i][j] = (f32x4){0.f, 0.f, 0.f, 0.f};

    auto compute = [&](int buf) {
        s16x8 af[4], bf[8];
#pragma unroll
        for (int fm = 0; fm < 4; ++fm) {
            int ra = wm * 64 + fm * 16 + (lane & 15);
            int sl = (lane >> 4) ^ (ra & 3);
            af[fm] = *(const s16x8*)&lds_a[buf][ra][sl * 8];
        }
#pragma unroll
        for (int fn = 0; fn < 8; ++fn) {
            int rb = wn * 128 + fn * 16 + (lane & 15);
            int sl = (lane >> 4) ^ (rb & 3);
            bf[fn] = *(const s16x8*)&lds_b[buf][rb][sl * 8];
        }
#pragma unroll
        for (int fm = 0; fm < 4; ++fm)
#pragma unroll
            for (int fn = 0; fn < 8; ++fn)
                acc[fm][fn] = __builtin_amdgcn_mfma_f32_16x16x32_bf16(af[fm], bf[fn], acc[fm][fn], 0, 0, 0);
    };

    // Prologue: stage tile 0
    loadA(0);
    stageB(0, 0);
    writeA(0);
    __syncthreads();

    const int nk = KDIM / BK;   // 16
    for (int t = 0; t < nk; ++t) {
        int cur = t & 1;
        if (t + 1 < nk) {
            loadA(t + 1);
            stageB(cur ^ 1, t + 1);
        }
        compute(cur);
        if (t + 1 < nk) writeA(cur ^ 1);
        __syncthreads();
    }

    const int lcol = lane & 15;
    const int lrg = (lane >> 4) * 4;

    if constexpr (EPI == 0) {
#pragma unroll
        for (int fm = 0; fm < 4; ++fm)
#pragma unroll
            for (int fn = 0; fn < 8; ++fn) {
                int col = wn * 128 + fn * 16 + lcol;
                float bias = b1[col] + b2[col];
#pragma unroll
                for (int reg = 0; reg < 4; ++reg) {
                    int row = r0 + wm * 64 + fm * 16 + lrg + reg;
                    outp[(size_t)row * KDIM + col] = acc[fm][fn][reg] + bias;
                }
            }
    } else {
        // Block rows span at most 2 batch indices (128 < 196): preload both attdec rows.
        const int b0 = r0 / NPIX;
        const int b1i = min(b0 + 1, BATCH - 1);
        float wfv[8], ad0[8], ad1[8];
        int colv[8];
#pragma unroll
        for (int fn = 0; fn < 8; ++fn) {
            colv[fn] = wn * 128 + fn * 16 + lcol;
            wfv[fn] = wfull[colv[fn]];
            ad0[fn] = attdec[(size_t)b0 * KDIM + colv[fn]];
            ad1[fn] = attdec[(size_t)b1i * KDIM + colv[fn]];
        }
        float* ebuf = reinterpret_cast<float*>(lds_b);   // [4 wn][128 rows], safe after final barrier
#pragma unroll
        for (int fm = 0; fm < 4; ++fm) {
#pragma unroll
            for (int reg = 0; reg < 4; ++reg) {
                int rl = wm * 64 + fm * 16 + lrg + reg;
                int row = r0 + rl;
                bool hi = (row / NPIX) != b0;
                float es = 0.f;
#pragma unroll
                for (int fn = 0; fn < 8; ++fn) {
                    float ad = hi ? ad1[fn] : ad0[fn];
                    float v = acc[fm][fn][reg] + ad;
                    v = fmaxf(v, 0.f);
                    es = fmaf(v, wfv[fn], es);
                }
#pragma unroll
                for (int m = 1; m < 16; m <<= 1) es += __shfl_xor(es, m);
                if (lcol == 0) ebuf[wn * BM + rl] = es;
            }
        }
        __syncthreads();
        if (tid < BM) {
            float s = (ebuf[tid] + ebuf[BM + tid]) + (ebuf[2 * BM + tid] + ebuf[3 * BM + tid]);
            outp[r0 + tid] = s;
        }
    }
}

// One block per batch element: softmax over 196 energies, write alpha,
// then context[b][e] = sum_p enc[b][p][e] * alpha[p].
__global__ void softmax_ctx(const float* __restrict__ enc, const float* __restrict__ energy,
                            float* __restrict__ out) {
    const int b = blockIdx.x;
    const int t = threadIdx.x;  // 256
    __shared__ float sal[NPIX];
    __shared__ float wred[4];

    float e = (t < NPIX) ? energy[b * NPIX + t] : -1e30f;
    float m = e;
#pragma unroll
    for (int d = 1; d < 64; d <<= 1) m = fmaxf(m, __shfl_xor(m, d));
    if ((t & 63) == 0) wred[t >> 6] = m;
    __syncthreads();
    m = fmaxf(fmaxf(wred[0], wred[1]), fmaxf(wred[2], wred[3]));

    float ex = (t < NPIX) ? __expf(e - m) : 0.f;
    float sm = ex;
#pragma unroll
    for (int d = 1; d < 64; d <<= 1) sm += __shfl_xor(sm, d);
    __syncthreads();
    if ((t & 63) == 0) wred[t >> 6] = sm;
    __syncthreads();
    sm = wred[0] + wred[1] + wred[2] + wred[3];

    float al = ex / sm;
    if (t < NPIX) {
        sal[t] = al;
        out[BATCH * KDIM + b * NPIX + t] = al;
    }
    __syncthreads();

    // context: each thread owns cols 2t, 2t+1
    float c0 = 0.f, c1 = 0.f;
    const float* eb = enc + (size_t)b * NPIX * KDIM;
    const int col = 2 * t;
    for (int p = 0; p < NPIX; ++p) {
        float a = sal[p];
        float2 v = *(const float2*)(eb + (size_t)p * KDIM + col);
        c0 = fmaf(v.x, a, c0);
        c1 = fmaf(v.y, a, c1);
    }
    out[b * KDIM + col] = c0;
    out[b * KDIM + col + 1] = c1;
}

extern "C" void kernel_launch(void* const* d_in, const int* in_sizes, int n_in,
                              void* d_out, int out_size, void* d_ws, size_t ws_size,
                              hipStream_t stream) {
    const float* encoder = (const float*)d_in[0];   // [512,196,512]
    const float* dec_h   = (const float*)d_in[1];   // [512,512]
    const float* W_enc   = (const float*)d_in[2];   // [512,512]
    const float* b_enc   = (const float*)d_in[3];   // [512]
    const float* W_dec   = (const float*)d_in[4];   // [512,512]
    const float* b_decv  = (const float*)d_in[5];   // [512]
    const float* w_full  = (const float*)d_in[6];   // [512]
    float* out = (float*)d_out;                     // context [512,512] ++ alpha [512,196]

    short* wt_enc = (short*)d_ws;                   // 512*512 bf16
    short* wt_dec = wt_enc + 512 * 512;             // 512*512 bf16
    float* attdec = (float*)(wt_dec + 512 * 512);   // [512][512] fp32 (incl. both biases)
    float* energy = attdec + 512 * 512;             // [100352] fp32

    // 1) weight transpose + bf16 convert
    prep_w<<<dim3(512, 2), 512, 0, stream>>>(W_enc, W_dec, wt_enc, wt_dec);

    // 2) att_dec' = dec_h @ W_dec + b_dec + b_enc   (store fp32 [512][512])
    gemm_fused<0><<<dim3(4), 512, 0, stream>>>(dec_h, 512, wt_dec,
                                               b_enc, b_decv, nullptr, nullptr, attdec);

    // 3) main fused GEMM -> full energies
    gemm_fused<1><<<dim3(M_MAIN / BM), 512, 0, stream>>>(encoder, M_MAIN, wt_enc,
                                                         nullptr, nullptr, attdec, w_full, energy);

    // 4) softmax + context
    softmax_ctx<<<dim3(BATCH), 256, 0, stream>>>(encoder, energy, out);
}

// Round 6
// 161.780 us; speedup vs baseline: 4.5142x; 4.5142x over previous
//
#include <hip/hip_runtime.h>
#include <hip/hip_bf16.h>
#include <cstdint>

#define KDIM 512
#define BM 256
#define BN 256
#define BK 64
#define M_MAIN 100352   // 512*196
#define NPIX 196
#define BATCH 512

typedef float f32x4 __attribute__((ext_vector_type(4)));
typedef short s16x8 __attribute__((ext_vector_type(8)));

__device__ __forceinline__ short f2bf(float f) {
    uint32_t u = __float_as_uint(f);
    uint32_t r = u + 0x7FFFu + ((u >> 16) & 1u);   // round-to-nearest-even
    return (short)(r >> 16);
}

__device__ __forceinline__ void gload_lds16(const void* g, void* l) {
    __builtin_amdgcn_global_load_lds(
        (const __attribute__((address_space(1))) void*)g,
        (__attribute__((address_space(3))) void*)l, 16, 0, 0);
}

__device__ __forceinline__ uint32_t pkbf(float lo, float hi) {
    __hip_bfloat162 p = __float22bfloat162_rn(float2{lo, hi});
    return *reinterpret_cast<uint32_t*>(&p);
}

// Transpose + convert W [K][A] fp32 -> Wt [A][K] bf16 for both weight matrices.
__global__ void prep_w(const float* __restrict__ W_enc, const float* __restrict__ W_dec,
                       short* __restrict__ Wt_enc, short* __restrict__ Wt_dec) {
    int a = blockIdx.x;
    int k = threadIdx.x;
    const float* W = blockIdx.y ? W_dec : W_enc;
    short* Wt = blockIdx.y ? Wt_dec : Wt_enc;
    Wt[a * KDIM + k] = f2bf(W[(size_t)k * KDIM + a]);
}

// 256x256 tile, BK=64, 512 threads = 8 waves (2M x 4N), wave-tile 128x64
// (acc[8][4]).  Counted-vmcnt pipelined loop (T3+T4): B via global_load_lds
// issued one tile ahead, A reg-staged+converted with globals issued TWO tiles
// ahead; per-tile barrier is raw s_barrier preceded by vmcnt(8) (B's 4 loads
// drained, A's 8 still in flight) + lgkmcnt(0).  LDS XOR-swizzle slot^(row&7)
// on both write and read sides (rule #21; B's global source pre-swizzled).
// EPI==0: out[row][col] = acc + b1[col] + b2[col]   (att_dec' precompute)
// EPI==1: energy partial per column-block: out[bx*M + row] =
//         sum_cols relu(acc + attdec[row/196][col]) * wfull[col]
template <int EPI>
__launch_bounds__(512, 2)
__global__ void gemm_fused(const float* __restrict__ A, int M,
                           const short* __restrict__ Bt,
                           const float* __restrict__ b1, const float* __restrict__ b2,
                           const float* __restrict__ attdec, const float* __restrict__ wfull,
                           float* __restrict__ outp) {
    __shared__ short lds_a[2][BM][BK];   // 64 KB
    __shared__ short lds_b[2][BN][BK];   // 64 KB

    const int tid = threadIdx.x;
    const int wave = tid >> 6;
    const int lane = tid & 63;
    const int wm = wave >> 2;       // 2 waves along M (128 rows each)
    const int wn = wave & 3;        // 4 waves along N (64 cols each)
    const int nwg = gridDim.x;
    int swzb;
    if ((nwg & 7) == 0) {
        int q = nwg >> 3;
        swzb = (blockIdx.x & 7) * q + (blockIdx.x >> 3);
    } else {
        swzb = blockIdx.x;
    }
    const int bx = swzb & 1;        // N/BN = 2 column blocks
    const int by = swzb >> 1;
    const int r0 = by * BM;
    const int c0 = bx * BN;

    f32x4 areg[4][2];               // 32 f32 per thread (one A K-tile)

    // A tile: 256 rows x 64 f32 = 2048 chunks of 8; thread owns chunks tid+512j.
    auto loadA = [&](int kt) {
#pragma unroll
        for (int j = 0; j < 4; ++j) {
            int g = tid + 512 * j;
            int row = g >> 3, col8 = (g & 7) * 8;
            const float* p = A + (size_t)(r0 + row) * KDIM + kt * BK + col8;
            areg[j][0] = *(const f32x4*)p;
            areg[j][1] = *(const f32x4*)(p + 4);
        }
    };
    auto writeA = [&](int buf) {
#pragma unroll
        for (int j = 0; j < 4; ++j) {
            int g = tid + 512 * j;
            int row = g >> 3;
            int slot = (g & 7) ^ (row & 7);           // XOR-swizzle 16B slot
            uint4 w;
            w.x = pkbf(areg[j][0][0], areg[j][0][1]);
            w.y = pkbf(areg[j][0][2], areg[j][0][3]);
            w.z = pkbf(areg[j][1][0], areg[j][1][1]);
            w.w = pkbf(areg[j][1][2], areg[j][1][3]);
            *reinterpret_cast<uint4*>(&lds_a[buf][row][slot * 8]) = w;
        }
    };
    auto stageB = [&](int buf, int kt) {
#pragma unroll
        for (int i = 0; i < 4; ++i) {
            int rb = wave * 32 + i * 8;     // 8 rows per issue (64 lanes * 16B)
            int srcslot = (lane & 7) ^ (lane >> 3);   // pre-swizzle SOURCE (rule #21)
            const short* g = Bt + (size_t)(c0 + rb + (lane >> 3)) * KDIM + kt * BK + srcslot * 8;
            gload_lds16(g, &lds_b[buf][rb][0]);
        }
    };

    f32x4 acc[8][4];
#pragma unroll
    for (int i = 0; i < 8; ++i)
#pragma unroll
        for (int j = 0; j < 4; ++j)
            acc[i][j] = (f32x4){0.f, 0.f, 0.f, 0.f};

    s16x8 af[8], bf[4];
    auto readFrags = [&](int buf, int kk) {
#pragma unroll
        for (int fm = 0; fm < 8; ++fm) {
            int ra = wm * 128 + fm * 16 + (lane & 15);
            int sl = (kk * 4 + (lane >> 4)) ^ (ra & 7);
            af[fm] = *(const s16x8*)&lds_a[buf][ra][sl * 8];
        }
#pragma unroll
        for (int fn = 0; fn < 4; ++fn) {
            int rb = wn * 64 + fn * 16 + (lane & 15);
            int sl = (kk * 4 + (lane >> 4)) ^ (rb & 7);
            bf[fn] = *(const s16x8*)&lds_b[buf][rb][sl * 8];
        }
    };
    auto mfmaAll = [&]() {
        __builtin_amdgcn_s_setprio(1);
#pragma unroll
        for (int fm = 0; fm < 8; ++fm)
#pragma unroll
            for (int fn = 0; fn < 4; ++fn)
                acc[fm][fn] = __builtin_amdgcn_mfma_f32_16x16x32_bf16(af[fm], bf[fn], acc[fm][fn], 0, 0, 0);
        __builtin_amdgcn_s_setprio(0);
    };

    // ---- prologue: tile 0 into buf0; A(1) globals in flight ----
    loadA(0);
    __builtin_amdgcn_sched_barrier(0);
    stageB(0, 0);                       // B(0) x4 (after A(0) x8 in vm queue)
    __builtin_amdgcn_sched_barrier(0);
    writeA(0);                          // compiler waits A(0) (vmcnt 4), cvt+write
    loadA(1);                           // A(1) x8 in flight
    __builtin_amdgcn_sched_barrier(0);
    asm volatile("s_waitcnt vmcnt(8)" ::: "memory");    // B(0) drained
    asm volatile("s_waitcnt lgkmcnt(0)" ::: "memory");  // A(0) writes visible
    __builtin_amdgcn_s_barrier();

    const int nk = KDIM / BK;   // 8
    for (int t = 0; t < nk - 1; ++t) {
        const int cur = t & 1;
        stageB(cur ^ 1, t + 1);         // B(t+1) x4 issued FIRST (oldest)
        __builtin_amdgcn_sched_barrier(0);
        readFrags(cur, 0);
        writeA(cur ^ 1);                // tile t+1 A into buf^1 (globals from prev iter)
        mfmaAll();                      // kk0: 32 MFMA
        readFrags(cur, 1);
        loadA(t + 2 < nk ? t + 2 : nk - 1);   // A(t+2) x8 (clamped; uniform vmcnt)
        __builtin_amdgcn_sched_barrier(0);
        mfmaAll();                      // kk1: 32 MFMA
        asm volatile("s_waitcnt vmcnt(8)" ::: "memory");    // B(t+1) done; A x8 in flight
        asm volatile("s_waitcnt lgkmcnt(0)" ::: "memory");  // A(t+1) writes visible
        __builtin_amdgcn_s_barrier();
    }
    // peeled last tile (buf1)
    readFrags(1, 0);
    mfmaAll();
    readFrags(1, 1);
    mfmaAll();

    const int lcol = lane & 15;
    const int lrg = (lane >> 4) * 4;

    if constexpr (EPI == 0) {
#pragma unroll
        for (int fm = 0; fm < 8; ++fm)
#pragma unroll
            for (int fn = 0; fn < 4; ++fn) {
                int col = c0 + wn * 64 + fn * 16 + lcol;
                float bias = b1[col] + b2[col];
#pragma unroll
                for (int reg = 0; reg < 4; ++reg) {
                    int row = r0 + wm * 128 + fm * 16 + lrg + reg;
                    outp[(size_t)row * KDIM + col] = acc[fm][fn][reg] + bias;
                }
            }
    } else {
        float wfv[4];
        int colv[4];
#pragma unroll
        for (int fn = 0; fn < 4; ++fn) {
            colv[fn] = c0 + wn * 64 + fn * 16 + lcol;
            wfv[fn] = wfull[colv[fn]];
        }
        // per-wave partial energies -> LDS (reuse lds_a[0] region; last tile read buf1)
        float* ebuf = reinterpret_cast<float*>(lds_a);   // [4 wn][256 rows]
#pragma unroll
        for (int fm = 0; fm < 8; ++fm) {
#pragma unroll
            for (int reg = 0; reg < 4; ++reg) {
                int rl = wm * 128 + fm * 16 + lrg + reg;
                int row = r0 + rl;
                int b = row / NPIX;
                float es = 0.f;
#pragma unroll
                for (int fn = 0; fn < 4; ++fn) {
                    float v = acc[fm][fn][reg] + attdec[(size_t)b * KDIM + colv[fn]];
                    v = fmaxf(v, 0.f);
                    es = fmaf(v, wfv[fn], es);
                }
#pragma unroll
                for (int m = 1; m < 16; m <<= 1) es += __shfl_xor(es, m);
                if (lcol == 0) ebuf[wn * BM + rl] = es;
            }
        }
        __syncthreads();
        if (tid < BM) {
            float s = (ebuf[tid] + ebuf[BM + tid]) + (ebuf[2 * BM + tid] + ebuf[3 * BM + tid]);
            outp[(size_t)bx * M + r0 + tid] = s;
        }
    }
}

// One block per batch element: sum 2 energy partials, softmax over 196, write alpha,
// then context[b][e] = sum_p enc[b][p][e] * alpha[p].
__global__ void softmax_ctx(const float* __restrict__ enc, const float* __restrict__ energy2,
                            float* __restrict__ out) {
    const int b = blockIdx.x;
    const int t = threadIdx.x;  // 256
    __shared__ float sal[NPIX];
    __shared__ float wred[4];

    float e = -1e30f;
    if (t < NPIX)
        e = energy2[b * NPIX + t] + energy2[(size_t)M_MAIN + b * NPIX + t];
    float m = e;
#pragma unroll
    for (int d = 1; d < 64; d <<= 1) m = fmaxf(m, __shfl_xor(m, d));
    if ((t & 63) == 0) wred[t >> 6] = m;
    __syncthreads();
    m = fmaxf(fmaxf(wred[0], wred[1]), fmaxf(wred[2], wred[3]));

    float ex = (t < NPIX) ? __expf(e - m) : 0.f;
    float sm = ex;
#pragma unroll
    for (int d = 1; d < 64; d <<= 1) sm += __shfl_xor(sm, d);
    __syncthreads();
    if ((t & 63) == 0) wred[t >> 6] = sm;
    __syncthreads();
    sm = wred[0] + wred[1] + wred[2] + wred[3];

    float al = ex / sm;
    if (t < NPIX) {
        sal[t] = al;
        out[BATCH * KDIM + b * NPIX + t] = al;
    }
    __syncthreads();

    // context: each thread owns cols 2t, 2t+1
    float c0 = 0.f, c1 = 0.f;
    const float* eb = enc + (size_t)b * NPIX * KDIM;
    const int col = 2 * t;
#pragma unroll 4
    for (int p = 0; p < NPIX; ++p) {
        float a = sal[p];
        float2 v = *(const float2*)(eb + (size_t)p * KDIM + col);
        c0 = fmaf(v.x, a, c0);
        c1 = fmaf(v.y, a, c1);
    }
    out[b * KDIM + col] = c0;
    out[b * KDIM + col + 1] = c1;
}

extern "C" void kernel_launch(void* const* d_in, const int* in_sizes, int n_in,
                              void* d_out, int out_size, void* d_ws, size_t ws_size,
                              hipStream_t stream) {
    const float* encoder = (const float*)d_in[0];   // [512,196,512]
    const float* dec_h   = (const float*)d_in[1];   // [512,512]
    const float* W_enc   = (const float*)d_in[2];   // [512,512]
    const float* b_enc   = (const float*)d_in[3];   // [512]
    const float* W_dec   = (const float*)d_in[4];   // [512,512]
    const float* b_decv  = (const float*)d_in[5];   // [512]
    const float* w_full  = (const float*)d_in[6];   // [512]
    float* out = (float*)d_out;                     // context [512,512] ++ alpha [512,196]

    short* wt_enc = (short*)d_ws;                   // 512*512 bf16
    short* wt_dec = wt_enc + 512 * 512;             // 512*512 bf16
    float* attdec = (float*)(wt_dec + 512 * 512);   // [512][512] fp32 (incl. both biases)
    float* energy2 = attdec + 512 * 512;            // [2][100352] fp32 partials

    // 1) weight transpose + bf16 convert
    prep_w<<<dim3(512, 2), 512, 0, stream>>>(W_enc, W_dec, wt_enc, wt_dec);

    // 2) att_dec' = dec_h @ W_dec + b_dec + b_enc   (store fp32 [512][512])
    gemm_fused<0><<<dim3(4), 512, 0, stream>>>(dec_h, 512, wt_dec,
                                               b_enc, b_decv, nullptr, nullptr, attdec);

    // 3) main fused GEMM -> energy partials (2 column-block slices)
    gemm_fused<1><<<dim3(2 * (M_MAIN / BM)), 512, 0, stream>>>(encoder, M_MAIN, wt_enc,
                                                               nullptr, nullptr, attdec, w_full, energy2);

    // 4) softmax + context
    softmax_ctx<<<dim3(BATCH), 256, 0, stream>>>(encoder, energy2, out);
}